// Round 2
// baseline (475.397 us; speedup 1.0000x reference)
//
#include <hip/hip_runtime.h>
#include <hip/hip_bf16.h>
#include <math.h>

#define DIM 768
#define NHEAD 12
#define HD 64
#define HIDDEN 384
#define BATCH 8
#define SEQ 1024
#define ROWS (BATCH*SEQ)
#define CHUNKB 2                 // batches per qkv/attn chunk
#define CHUNKR (CHUNKB*SEQ)      // 2048 rows

typedef short bf16x8 __attribute__((ext_vector_type(8)));
typedef float f32x4 __attribute__((ext_vector_type(4)));
typedef unsigned short u16;

__device__ __forceinline__ u16 f2bs(float f) {
    unsigned int u = __float_as_uint(f);
    unsigned int r = (u + 0x7FFFu + ((u >> 16) & 1u)) >> 16;
    return (u16)r;
}

// ---------------- weight convert + transpose: Wt[n][k] = bf16(W[k][n]) ----------------
__global__ __launch_bounds__(256) void wtrans(const float* __restrict__ W,
                                              u16* __restrict__ Wt, int K, int N) {
    int i = blockIdx.x * 256 + threadIdx.x;
    int total = K * N;
    if (i >= total) return;
    int n = i / K;
    int k = i - n * K;
    Wt[i] = f2bs(W[(long)k * N + n]);
}

// ---------------- layernorm: fp32 in -> bf16 out, one block per row ----------------
__global__ __launch_bounds__(256) void lnorm(const float* __restrict__ X,
                                             const float* __restrict__ w,
                                             const float* __restrict__ b,
                                             u16* __restrict__ Y) {
    int row = blockIdx.x;
    const float* xr = X + (long)row * DIM;
    int t = threadIdx.x;
    float v0 = xr[t], v1 = xr[t + 256], v2 = xr[t + 512];
    float s = v0 + v1 + v2;
    float s2 = v0 * v0 + v1 * v1 + v2 * v2;
    for (int off = 1; off < 64; off <<= 1) {
        s  += __shfl_xor(s,  off, 64);
        s2 += __shfl_xor(s2, off, 64);
    }
    __shared__ float ss[4], ss2[4];
    int wid = t >> 6;
    if ((t & 63) == 0) { ss[wid] = s; ss2[wid] = s2; }
    __syncthreads();
    s  = ss[0] + ss[1] + ss[2] + ss[3];
    s2 = ss2[0] + ss2[1] + ss2[2] + ss2[3];
    float mu = s * (1.0f / DIM);
    float var = s2 * (1.0f / DIM) - mu * mu;
    float rstd = rsqrtf(var + 1e-5f);
    u16* yr = Y + (long)row * DIM;
    yr[t]       = f2bs((v0 - mu) * rstd * w[t]       + b[t]);
    yr[t + 256] = f2bs((v1 - mu) * rstd * w[t + 256] + b[t + 256]);
    yr[t + 512] = f2bs((v2 - mu) * rstd * w[t + 512] + b[t + 512]);
}

// ---------------- bf16 MFMA GEMM, C = A[M,K] @ Bt[N,K]^T, 128x128x32 tiles ----------------
// EPI: 0 = bf16 out; 1 = f32 out + resid; 2 = bf16 out + bias + exact GELU; 3 = f32 out + resid + bias
template <int EPI>
__global__ __launch_bounds__(256) void gemm_bt(const u16* __restrict__ A,
                                               const u16* __restrict__ Bt,
                                               int M, int N, int K,
                                               u16* __restrict__ Cb,
                                               float* __restrict__ Cf,
                                               const float* __restrict__ resid,
                                               const float* __restrict__ bias) {
    __shared__ u16 As[128 * 40];
    __shared__ u16 Bs[128 * 40];
    int m0 = blockIdx.y * 128;
    int n0 = blockIdx.x * 128;
    int t = threadIdx.x;
    int lane = t & 63, w = t >> 6;
    int quad = lane >> 4, l16 = lane & 15;
    int wr = w >> 1, wc = w & 1;

    f32x4 acc[4][4];
#pragma unroll
    for (int mb = 0; mb < 4; mb++)
#pragma unroll
        for (int nb = 0; nb < 4; nb++) acc[mb][nb] = (f32x4){0.f, 0.f, 0.f, 0.f};

    for (int kt = 0; kt < K; kt += 32) {
        __syncthreads();
#pragma unroll
        for (int cc = 0; cc < 2; cc++) {
            int c = t + cc * 256;
            int row = c >> 2, off = (c & 3) * 8;
            *(bf16x8*)&As[row * 40 + off] = *(const bf16x8*)&A[(long)(m0 + row) * K + kt + off];
            *(bf16x8*)&Bs[row * 40 + off] = *(const bf16x8*)&Bt[(long)(n0 + row) * K + kt + off];
        }
        __syncthreads();
        bf16x8 af[4], bfr[4];
#pragma unroll
        for (int mb = 0; mb < 4; mb++)
            af[mb] = *(const bf16x8*)&As[(wr * 64 + mb * 16 + l16) * 40 + quad * 8];
#pragma unroll
        for (int nb = 0; nb < 4; nb++)
            bfr[nb] = *(const bf16x8*)&Bs[(wc * 64 + nb * 16 + l16) * 40 + quad * 8];
#pragma unroll
        for (int mb = 0; mb < 4; mb++)
#pragma unroll
            for (int nb = 0; nb < 4; nb++)
                acc[mb][nb] = __builtin_amdgcn_mfma_f32_16x16x32_bf16(af[mb], bfr[nb], acc[mb][nb], 0, 0, 0);
    }

    int mbase = m0 + wr * 64, nbase = n0 + wc * 64;
#pragma unroll
    for (int mb = 0; mb < 4; mb++)
#pragma unroll
        for (int nb = 0; nb < 4; nb++) {
            int r0 = mbase + mb * 16 + quad * 4;
            int c = nbase + nb * 16 + l16;
#pragma unroll
            for (int r = 0; r < 4; r++) {
                float v = acc[mb][nb][r];
                long idx = (long)(r0 + r) * N + c;
                if (EPI == 0) {
                    Cb[idx] = f2bs(v);
                } else if (EPI == 1) {
                    Cf[idx] = resid[idx] + v;
                } else if (EPI == 2) {
                    float xg = v + bias[c];
                    Cb[idx] = f2bs(xg * 0.5f * (1.0f + erff(xg * 0.70710678118f)));
                } else {
                    Cf[idx] = resid[idx] + v + bias[c];
                }
            }
        }
}

// ---------------- flash attention: one block per (qtile, head, local-batch) ----------------
// QKV bf16 [nb*S, 3*DIM]; Q at col h*64, K at 768+h*64, V at 1536+h*64. logits *= 8.
// O is bf16 [nb*S, DIM], O row = b*SEQ + q (b local to this chunk).
__global__ __launch_bounds__(256) void attn(const u16* __restrict__ QKV, u16* __restrict__ O) {
    __shared__ u16 Ks[64 * 72];
    __shared__ u16 Vs[64 * 72];       // transposed: Vs[d][kv]
    __shared__ u16 Ps[4][16 * 72];    // per-wave P tile [m][kv]
    int q0 = blockIdx.x * 64;
    int h = blockIdx.y;
    int b = blockIdx.z;
    int t = threadIdx.x;
    int lane = t & 63, w = t >> 6;
    int quad = lane >> 4, l16 = lane & 15;

    const long rs = 3 * DIM;  // 2304
    const u16* base = QKV + (long)b * SEQ * rs;

    int qrow = q0 + w * 16 + l16;
    bf16x8 qf0 = *(const bf16x8*)&base[(long)qrow * rs + h * 64 + quad * 8];
    bf16x8 qf1 = *(const bf16x8*)&base[(long)qrow * rs + h * 64 + 32 + quad * 8];

    f32x4 o[4];
#pragma unroll
    for (int jb = 0; jb < 4; jb++) o[jb] = (f32x4){0.f, 0.f, 0.f, 0.f};
    float m_run[4], l_run[4];
#pragma unroll
    for (int r = 0; r < 4; r++) { m_run[r] = -1e30f; l_run[r] = 0.f; }

    for (int kt = 0; kt < SEQ; kt += 64) {
        __syncthreads();
        {
            int kv = t >> 2, off = (t & 3) * 16;
            const u16* krow = &base[(long)(kt + kv) * rs + DIM + h * 64 + off];
            *(bf16x8*)&Ks[kv * 72 + off]     = *(const bf16x8*)&krow[0];
            *(bf16x8*)&Ks[kv * 72 + off + 8] = *(const bf16x8*)&krow[8];
            const u16* vrow = &base[(long)(kt + kv) * rs + 2 * DIM + h * 64 + off];
            u16 vv[16];
            *(bf16x8*)&vv[0] = *(const bf16x8*)&vrow[0];
            *(bf16x8*)&vv[8] = *(const bf16x8*)&vrow[8];
#pragma unroll
            for (int j = 0; j < 16; j++) Vs[(off + j) * 72 + kv] = vv[j];
        }
        __syncthreads();

        f32x4 s[4];
#pragma unroll
        for (int jb = 0; jb < 4; jb++) {
            bf16x8 kf0 = *(const bf16x8*)&Ks[(jb * 16 + l16) * 72 + quad * 8];
            bf16x8 kf1 = *(const bf16x8*)&Ks[(jb * 16 + l16) * 72 + 32 + quad * 8];
            f32x4 z = (f32x4){0.f, 0.f, 0.f, 0.f};
            z = __builtin_amdgcn_mfma_f32_16x16x32_bf16(qf0, kf0, z, 0, 0, 0);
            z = __builtin_amdgcn_mfma_f32_16x16x32_bf16(qf1, kf1, z, 0, 0, 0);
            s[jb] = z;
        }
#pragma unroll
        for (int jb = 0; jb < 4; jb++)
#pragma unroll
            for (int r = 0; r < 4; r++) s[jb][r] *= 8.0f;

        float alpha[4];
#pragma unroll
        for (int r = 0; r < 4; r++) {
            float m1 = fmaxf(fmaxf(s[0][r], s[1][r]), fmaxf(s[2][r], s[3][r]));
            for (int off = 1; off < 16; off <<= 1) m1 = fmaxf(m1, __shfl_xor(m1, off, 64));
            float mn = fmaxf(m_run[r], m1);
            alpha[r] = __expf(m_run[r] - mn);
            m_run[r] = mn;
            float rsum = 0.f;
#pragma unroll
            for (int jb = 0; jb < 4; jb++) {
                float p = __expf(s[jb][r] - mn);
                s[jb][r] = p;
                rsum += p;
            }
            for (int off = 1; off < 16; off <<= 1) rsum += __shfl_xor(rsum, off, 64);
            l_run[r] = l_run[r] * alpha[r] + rsum;
#pragma unroll
            for (int jb = 0; jb < 4; jb++) o[jb][r] *= alpha[r];
        }

#pragma unroll
        for (int jb = 0; jb < 4; jb++)
#pragma unroll
            for (int r = 0; r < 4; r++)
                Ps[w][(quad * 4 + r) * 72 + jb * 16 + l16] = f2bs(s[jb][r]);
        __syncthreads();

#pragma unroll
        for (int c = 0; c < 2; c++) {
            bf16x8 pf = *(const bf16x8*)&Ps[w][l16 * 72 + c * 32 + quad * 8];
#pragma unroll
            for (int jb = 0; jb < 4; jb++) {
                bf16x8 vf = *(const bf16x8*)&Vs[(jb * 16 + l16) * 72 + c * 32 + quad * 8];
                o[jb] = __builtin_amdgcn_mfma_f32_16x16x32_bf16(pf, vf, o[jb], 0, 0, 0);
            }
        }
    }

    u16* orow = O + ((long)(b * SEQ + q0 + w * 16)) * DIM + h * 64;
#pragma unroll
    for (int jb = 0; jb < 4; jb++)
#pragma unroll
        for (int r = 0; r < 4; r++) {
            float v = o[jb][r] / l_run[r];
            orow[(long)(quad * 4 + r) * DIM + jb * 16 + l16] = f2bs(v);
        }
}

extern "C" void kernel_launch(void* const* d_in, const int* in_sizes, int n_in,
                              void* d_out, int out_size, void* d_ws, size_t ws_size,
                              hipStream_t stream) {
    const float* x     = (const float*)d_in[0];
    const float* ln1w  = (const float*)d_in[1];
    const float* ln1b  = (const float*)d_in[2];
    const float* ln2w  = (const float*)d_in[3];
    const float* ln2b  = (const float*)d_in[4];
    const float* wqkv  = (const float*)d_in[5];
    const float* wproj = (const float*)d_in[6];
    const float* wfc1  = (const float*)d_in[7];
    const float* bfc1  = (const float*)d_in[8];
    const float* wfc2  = (const float*)d_in[9];
    const float* bfc2  = (const float*)d_in[10];
    float* out = (float*)d_out;   // also used as x1 storage (fp32 ROWS*DIM)

    // ---- workspace layout: total ~27.9 MB (ws overflow in R0 corrupted
    // neighboring allocations -> post-timing divergence; keep this tight) ----
    char* ws = (char*)d_ws;
    size_t off = 0;
    auto alloc = [&](size_t bytes) {
        void* p = ws + off;
        off = (off + bytes + 255) & ~(size_t)255;
        return p;
    };
    u16* wt_qkv  = (u16*)alloc((size_t)3 * DIM * DIM * 2);   // 3.54 MB
    u16* wt_proj = (u16*)alloc((size_t)DIM * DIM * 2);       // 1.18 MB
    u16* wt_fc1  = (u16*)alloc((size_t)HIDDEN * DIM * 2);    // 0.59 MB
    u16* wt_fc2  = (u16*)alloc((size_t)DIM * HIDDEN * 2);    // 0.59 MB
    u16* hbuf    = (u16*)alloc((size_t)ROWS * DIM * 2);      // 12.58 MB: ln1 out / attn out / ln2 out
    u16* qchunk  = (u16*)alloc((size_t)CHUNKR * 3 * DIM * 2);// 9.44 MB: qkv chunk, later gelu out (6.29 MB)

    // 1. weights -> bf16 transposed
    wtrans<<<(DIM * 3 * DIM + 255) / 256, 256, 0, stream>>>(wqkv, wt_qkv, DIM, 3 * DIM);
    wtrans<<<(DIM * DIM + 255) / 256, 256, 0, stream>>>(wproj, wt_proj, DIM, DIM);
    wtrans<<<(DIM * HIDDEN + 255) / 256, 256, 0, stream>>>(wfc1, wt_fc1, DIM, HIDDEN);
    wtrans<<<(DIM * HIDDEN + 255) / 256, 256, 0, stream>>>(wfc2, wt_fc2, HIDDEN, DIM);

    // 2. ln1: hbuf = LN(x)
    lnorm<<<ROWS, 256, 0, stream>>>(x, ln1w, ln1b, hbuf);

    // 3. per-chunk: qkv GEMM then attention (attn out overwrites consumed ln1 rows)
    for (int c = 0; c < ROWS / CHUNKR; c++) {
        const u16* hA = hbuf + (size_t)c * CHUNKR * DIM;
        gemm_bt<0><<<dim3(3 * DIM / 128, CHUNKR / 128), 256, 0, stream>>>(
            hA, wt_qkv, CHUNKR, 3 * DIM, DIM, qchunk, nullptr, nullptr, nullptr);
        attn<<<dim3(SEQ / 64, NHEAD, CHUNKB), 256, 0, stream>>>(
            qchunk, hbuf + (size_t)c * CHUNKR * DIM);
    }

    // 4. x1 = x + attn_out @ w_proj  (fp32, stored in d_out)
    gemm_bt<1><<<dim3(DIM / 128, ROWS / 128), 256, 0, stream>>>(
        hbuf, wt_proj, ROWS, DIM, DIM, nullptr, out, x, nullptr);

    // 5. ln2: hbuf = LN(x1)
    lnorm<<<ROWS, 256, 0, stream>>>(out, ln2w, ln2b, hbuf);

    // 6. g = gelu(hbuf @ w_fc1 + b_fc1)  (bf16, reuse qchunk)
    gemm_bt<2><<<dim3(HIDDEN / 128, ROWS / 128), 256, 0, stream>>>(
        hbuf, wt_fc1, ROWS, HIDDEN, DIM, qchunk, nullptr, nullptr, bfc1);

    // 7. out = x1 + g @ w_fc2 + b_fc2  (fp32, in-place over x1 in d_out)
    gemm_bt<3><<<dim3(DIM / 128, ROWS / 128), 256, 0, stream>>>(
        qchunk, wt_fc2, ROWS, DIM, HIDDEN, nullptr, out, out, bfc2);
}

// Round 3
// 349.467 us; speedup vs baseline: 1.3603x; 1.3603x over previous
//
#include <hip/hip_runtime.h>
#include <hip/hip_bf16.h>
#include <math.h>

#define DIM 768
#define NHEAD 12
#define HD 64
#define HIDDEN 384
#define BATCH 8
#define SEQ 1024
#define ROWS (BATCH*SEQ)
#define CHUNKB 4                 // batches per qkv/attn chunk
#define CHUNKR (CHUNKB*SEQ)      // 4096 rows

typedef short bf16x8 __attribute__((ext_vector_type(8)));
typedef float f32x4 __attribute__((ext_vector_type(4)));
typedef unsigned short u16;
typedef unsigned int u32;

__device__ __forceinline__ u16 f2bs(float f) {
    unsigned int u = __float_as_uint(f);
    unsigned int r = (u + 0x7FFFu + ((u >> 16) & 1u)) >> 16;
    return (u16)r;
}

// ---------------- tiled weight transpose: Wt[n][k] = bf16(W[k][n]) ----------------
__global__ __launch_bounds__(256) void wtrans(const float* __restrict__ W,
                                              u16* __restrict__ Wt, int K, int N) {
    __shared__ float tile[32][33];
    int n0 = blockIdx.x * 32, k0 = blockIdx.y * 32;
    int tx = threadIdx.x & 31, ty = threadIdx.x >> 5;  // ty 0..7
#pragma unroll
    for (int i = 0; i < 4; i++)
        tile[ty + i * 8][tx] = W[(long)(k0 + ty + i * 8) * N + n0 + tx];
    __syncthreads();
#pragma unroll
    for (int i = 0; i < 4; i++)
        Wt[(long)(n0 + ty + i * 8) * K + k0 + tx] = f2bs(tile[tx][ty + i * 8]);
}

// ---------------- layernorm: fp32 in -> bf16 out, one block per row ----------------
__global__ __launch_bounds__(256) void lnorm(const float* __restrict__ X,
                                             const float* __restrict__ w,
                                             const float* __restrict__ b,
                                             u16* __restrict__ Y) {
    int row = blockIdx.x;
    const float* xr = X + (long)row * DIM;
    int t = threadIdx.x;
    float v0 = xr[t], v1 = xr[t + 256], v2 = xr[t + 512];
    float s = v0 + v1 + v2;
    float s2 = v0 * v0 + v1 * v1 + v2 * v2;
    for (int off = 1; off < 64; off <<= 1) {
        s  += __shfl_xor(s,  off, 64);
        s2 += __shfl_xor(s2, off, 64);
    }
    __shared__ float ss[4], ss2[4];
    int wid = t >> 6;
    if ((t & 63) == 0) { ss[wid] = s; ss2[wid] = s2; }
    __syncthreads();
    s  = ss[0] + ss[1] + ss[2] + ss[3];
    s2 = ss2[0] + ss2[1] + ss2[2] + ss2[3];
    float mu = s * (1.0f / DIM);
    float var = s2 * (1.0f / DIM) - mu * mu;
    float rstd = rsqrtf(var + 1e-5f);
    u16* yr = Y + (long)row * DIM;
    yr[t]       = f2bs((v0 - mu) * rstd * w[t]       + b[t]);
    yr[t + 256] = f2bs((v1 - mu) * rstd * w[t + 256] + b[t + 256]);
    yr[t + 512] = f2bs((v2 - mu) * rstd * w[t + 512] + b[t + 512]);
}

// ---------------- bf16 MFMA GEMM, C = A[M,K] @ Bt[N,K]^T, BMxBNx32 tiles ----------------
// EPI: 0 = bf16 out; 1 = f32 out + resid; 2 = bf16 out + bias + exact GELU; 3 = f32 out + resid + bias
template <int BM, int BN, int EPI>
__global__ __launch_bounds__(256) void gemm_bt(const u16* __restrict__ A,
                                               const u16* __restrict__ Bt,
                                               int M, int N, int K,
                                               u16* __restrict__ Cb,
                                               float* __restrict__ Cf,
                                               const float* __restrict__ resid,
                                               const float* __restrict__ bias) {
    constexpr int MB = BM / 32, NB = BN / 32;
    __shared__ u16 As[BM * 40];
    __shared__ u16 Bs[BN * 40];
    int m0 = blockIdx.y * BM;
    int n0 = blockIdx.x * BN;
    int t = threadIdx.x;
    int lane = t & 63, w = t >> 6;
    int quad = lane >> 4, l16 = lane & 15;
    int wr = w >> 1, wc = w & 1;

    f32x4 acc[MB][NB];
#pragma unroll
    for (int mb = 0; mb < MB; mb++)
#pragma unroll
        for (int nb = 0; nb < NB; nb++) acc[mb][nb] = (f32x4){0.f, 0.f, 0.f, 0.f};

    for (int kt = 0; kt < K; kt += 32) {
        __syncthreads();
#pragma unroll
        for (int i = 0; i < BM / 64; i++) {
            int c = t + i * 256;
            int row = c >> 2, off = (c & 3) * 8;
            *(bf16x8*)&As[row * 40 + off] = *(const bf16x8*)&A[(long)(m0 + row) * K + kt + off];
        }
#pragma unroll
        for (int i = 0; i < BN / 64; i++) {
            int c = t + i * 256;
            int row = c >> 2, off = (c & 3) * 8;
            *(bf16x8*)&Bs[row * 40 + off] = *(const bf16x8*)&Bt[(long)(n0 + row) * K + kt + off];
        }
        __syncthreads();
        bf16x8 af[MB], bfr[NB];
#pragma unroll
        for (int mb = 0; mb < MB; mb++)
            af[mb] = *(const bf16x8*)&As[(wr * (BM / 2) + mb * 16 + l16) * 40 + quad * 8];
#pragma unroll
        for (int nb = 0; nb < NB; nb++)
            bfr[nb] = *(const bf16x8*)&Bs[(wc * (BN / 2) + nb * 16 + l16) * 40 + quad * 8];
#pragma unroll
        for (int mb = 0; mb < MB; mb++)
#pragma unroll
            for (int nb = 0; nb < NB; nb++)
                acc[mb][nb] = __builtin_amdgcn_mfma_f32_16x16x32_bf16(af[mb], bfr[nb], acc[mb][nb], 0, 0, 0);
    }

    int mbase = m0 + wr * (BM / 2), nbase = n0 + wc * (BN / 2);
#pragma unroll
    for (int mb = 0; mb < MB; mb++)
#pragma unroll
        for (int nb = 0; nb < NB; nb++) {
            int r0 = mbase + mb * 16 + quad * 4;
            int c = nbase + nb * 16 + l16;
#pragma unroll
            for (int r = 0; r < 4; r++) {
                float v = acc[mb][nb][r];
                long idx = (long)(r0 + r) * N + c;
                if (EPI == 0) {
                    Cb[idx] = f2bs(v);
                } else if (EPI == 1) {
                    Cf[idx] = resid[idx] + v;
                } else if (EPI == 2) {
                    float xg = v + bias[c];
                    Cb[idx] = f2bs(xg * 0.5f * (1.0f + erff(xg * 0.70710678118f)));
                } else {
                    Cf[idx] = resid[idx] + v + bias[c];
                }
            }
        }
}

// ---------------- flash attention: one block per (qtile=64, head, local-batch) ----------------
// QKV bf16 [nb*S, 3*DIM]; Q at col h*64, K at 768+h*64, V at 1536+h*64. softmax over 8*logits.
// O written to Obuf rows [b*SEQ + q][DIM] at col h*64.
__global__ __launch_bounds__(256) void attn(const u16* __restrict__ QKV, u16* __restrict__ O) {
    __shared__ u16 Ks[64 * 72];
    __shared__ u16 Vs[64 * 72];       // transposed: Vs[d][kv]
    __shared__ u16 Ps[4][16 * 72];    // per-wave P tile [m][kv] (wave-private)
    int q0 = blockIdx.x * 64;
    int h = blockIdx.y;
    int b = blockIdx.z;
    int t = threadIdx.x;
    int lane = t & 63, w = t >> 6;
    int quad = lane >> 4, l16 = lane & 15;

    const long rs = 3 * DIM;  // 2304
    const u16* base = QKV + (long)b * SEQ * rs;

    int qrow = q0 + w * 16 + l16;
    bf16x8 qf0 = *(const bf16x8*)&base[(long)qrow * rs + h * 64 + quad * 8];
    bf16x8 qf1 = *(const bf16x8*)&base[(long)qrow * rs + h * 64 + 32 + quad * 8];

    f32x4 o[4];
#pragma unroll
    for (int jb = 0; jb < 4; jb++) o[jb] = (f32x4){0.f, 0.f, 0.f, 0.f};
    float m_run[4], l_run[4];
#pragma unroll
    for (int r = 0; r < 4; r++) { m_run[r] = -1e30f; l_run[r] = 0.f; }

    // V staging decomposition: kv-pair p = t&31, d-octet o = t>>5
    int vp = t & 31, vo = t >> 5;

    for (int kt = 0; kt < SEQ; kt += 64) {
        __syncthreads();
        {
            // K: rows kv, 16 elems per thread, b128 writes
            int kv = t >> 2, koff = (t & 3) * 16;
            const u16* krow = &base[(long)(kt + kv) * rs + DIM + h * 64 + koff];
            *(bf16x8*)&Ks[kv * 72 + koff]     = *(const bf16x8*)&krow[0];
            *(bf16x8*)&Ks[kv * 72 + koff + 8] = *(const bf16x8*)&krow[8];
            // V transposed: load 8 d-values for kv pair (2*vp, 2*vp+1), pack pairs -> b32 writes
            const u16* v0r = &base[(long)(kt + 2 * vp) * rs + 2 * DIM + h * 64 + vo * 8];
            const u16* v1r = v0r + rs;
            bf16x8 va = *(const bf16x8*)v0r;
            bf16x8 vb = *(const bf16x8*)v1r;
#pragma unroll
            for (int j = 0; j < 8; j++) {
                u32 pk = (u32)(u16)va[j] | ((u32)(u16)vb[j] << 16);
                *(u32*)&Vs[(vo * 8 + j) * 72 + 2 * vp] = pk;
            }
        }
        __syncthreads();

        f32x4 s[4];
#pragma unroll
        for (int jb = 0; jb < 4; jb++) {
            bf16x8 kf0 = *(const bf16x8*)&Ks[(jb * 16 + l16) * 72 + quad * 8];
            bf16x8 kf1 = *(const bf16x8*)&Ks[(jb * 16 + l16) * 72 + 32 + quad * 8];
            f32x4 z = (f32x4){0.f, 0.f, 0.f, 0.f};
            z = __builtin_amdgcn_mfma_f32_16x16x32_bf16(qf0, kf0, z, 0, 0, 0);
            z = __builtin_amdgcn_mfma_f32_16x16x32_bf16(qf1, kf1, z, 0, 0, 0);
            s[jb] = z;
        }

        // online softmax over 8*s (scale folded into exp args; max kept in raw units)
        float alpha[4];
#pragma unroll
        for (int r = 0; r < 4; r++) {
            float m1 = fmaxf(fmaxf(s[0][r], s[1][r]), fmaxf(s[2][r], s[3][r]));
            for (int off = 1; off < 16; off <<= 1) m1 = fmaxf(m1, __shfl_xor(m1, off, 64));
            float mn = fmaxf(m_run[r], m1);
            alpha[r] = __expf((m_run[r] - mn) * 8.0f);
            m_run[r] = mn;
            float rsum = 0.f;
#pragma unroll
            for (int jb = 0; jb < 4; jb++) {
                float p = __expf((s[jb][r] - mn) * 8.0f);
                s[jb][r] = p;
                rsum += p;
            }
            for (int off = 1; off < 16; off <<= 1) rsum += __shfl_xor(rsum, off, 64);
            l_run[r] = l_run[r] * alpha[r] + rsum;
#pragma unroll
            for (int jb = 0; jb < 4; jb++) o[jb][r] *= alpha[r];
        }

        // P -> LDS (wave-private; same-wave lgkm ordering, no barrier needed)
#pragma unroll
        for (int jb = 0; jb < 4; jb++)
#pragma unroll
            for (int r = 0; r < 4; r++)
                Ps[w][(quad * 4 + r) * 72 + jb * 16 + l16] = f2bs(s[jb][r]);

#pragma unroll
        for (int c = 0; c < 2; c++) {
            bf16x8 pf = *(const bf16x8*)&Ps[w][l16 * 72 + c * 32 + quad * 8];
#pragma unroll
            for (int jb = 0; jb < 4; jb++) {
                bf16x8 vf = *(const bf16x8*)&Vs[(jb * 16 + l16) * 72 + c * 32 + quad * 8];
                o[jb] = __builtin_amdgcn_mfma_f32_16x16x32_bf16(pf, vf, o[jb], 0, 0, 0);
            }
        }
    }

    u16* orow = O + ((long)(b * SEQ + q0 + w * 16)) * DIM + h * 64;
#pragma unroll
    for (int jb = 0; jb < 4; jb++)
#pragma unroll
        for (int r = 0; r < 4; r++) {
            float v = o[jb][r] / l_run[r];
            orow[(long)(quad * 4 + r) * DIM + jb * 16 + l16] = f2bs(v);
        }
}

extern "C" void kernel_launch(void* const* d_in, const int* in_sizes, int n_in,
                              void* d_out, int out_size, void* d_ws, size_t ws_size,
                              hipStream_t stream) {
    const float* x     = (const float*)d_in[0];
    const float* ln1w  = (const float*)d_in[1];
    const float* ln1b  = (const float*)d_in[2];
    const float* ln2w  = (const float*)d_in[3];
    const float* ln2b  = (const float*)d_in[4];
    const float* wqkv  = (const float*)d_in[5];
    const float* wproj = (const float*)d_in[6];
    const float* wfc1  = (const float*)d_in[7];
    const float* bfc1  = (const float*)d_in[8];
    const float* wfc2  = (const float*)d_in[9];
    const float* bfc2  = (const float*)d_in[10];
    float* out = (float*)d_out;

    // ---- ws layout: 24.8 MB total (proven-safe bound ~28 MB from R1/R2).
    // d_out (25.2 MB fp32) doubles as the qkv chunk buffer (18.9 MB bf16) until proj,
    // then holds x1 / final output.
    char* ws = (char*)d_ws;
    size_t off = 0;
    auto alloc = [&](size_t bytes) {
        void* p = ws + off;
        off = (off + bytes + 255) & ~(size_t)255;
        return p;
    };
    u16* wt_qkv  = (u16*)alloc((size_t)3 * DIM * DIM * 2);   // 3.54 MB
    u16* wt_proj = (u16*)alloc((size_t)DIM * DIM * 2);       // 1.18 MB
    u16* wt_fc1  = (u16*)alloc((size_t)HIDDEN * DIM * 2);    // 0.59 MB
    u16* wt_fc2  = (u16*)alloc((size_t)DIM * HIDDEN * 2);    // 0.59 MB
    u16* hbuf    = (u16*)alloc((size_t)ROWS * DIM * 2);      // 12.58 MB: ln1 out -> attn out -> ln2 out
    u16* gbuf    = (u16*)alloc((size_t)ROWS * HIDDEN * 2);   // 6.29 MB: gelu out
    u16* qd      = (u16*)d_out;                              // qkv chunk (bf16) lives in d_out

    // 1. weights -> bf16 transposed (tiled, coalesced)
    wtrans<<<dim3(3 * DIM / 32, DIM / 32), 256, 0, stream>>>(wqkv, wt_qkv, DIM, 3 * DIM);
    wtrans<<<dim3(DIM / 32, DIM / 32), 256, 0, stream>>>(wproj, wt_proj, DIM, DIM);
    wtrans<<<dim3(HIDDEN / 32, DIM / 32), 256, 0, stream>>>(wfc1, wt_fc1, DIM, HIDDEN);
    wtrans<<<dim3(DIM / 32, HIDDEN / 32), 256, 0, stream>>>(wfc2, wt_fc2, HIDDEN, DIM);

    // 2. ln1: hbuf = LN(x)
    lnorm<<<ROWS, 256, 0, stream>>>(x, ln1w, ln1b, hbuf);

    // 3. per-chunk (4 batches): qkv GEMM into d_out, attn writes O into hbuf
    //    (overwriting that chunk's already-consumed ln1 rows)
    for (int c = 0; c < ROWS / CHUNKR; c++) {
        const u16* hA = hbuf + (size_t)c * CHUNKR * DIM;
        gemm_bt<128, 128, 0><<<dim3(3 * DIM / 128, CHUNKR / 128), 256, 0, stream>>>(
            hA, wt_qkv, CHUNKR, 3 * DIM, DIM, qd, nullptr, nullptr, nullptr);
        attn<<<dim3(SEQ / 64, NHEAD, CHUNKB), 256, 0, stream>>>(
            qd, hbuf + (size_t)c * CHUNKR * DIM);
    }

    // 4. x1 = x + attn_out @ w_proj  (fp32 into d_out; qkv chunk dead)
    gemm_bt<128, 64, 1><<<dim3(DIM / 64, ROWS / 128), 256, 0, stream>>>(
        hbuf, wt_proj, ROWS, DIM, DIM, nullptr, out, x, nullptr);

    // 5. ln2: hbuf = LN(x1)
    lnorm<<<ROWS, 256, 0, stream>>>(out, ln2w, ln2b, hbuf);

    // 6. g = gelu(hbuf @ w_fc1 + b_fc1)  (bf16 into gbuf)
    gemm_bt<64, 64, 2><<<dim3(HIDDEN / 64, ROWS / 64), 256, 0, stream>>>(
        hbuf, wt_fc1, ROWS, HIDDEN, DIM, gbuf, nullptr, nullptr, bfc1);

    // 7. out = x1 + g @ w_fc2 + b_fc2  (fp32, in-place over x1)
    gemm_bt<128, 64, 3><<<dim3(DIM / 64, ROWS / 128), 256, 0, stream>>>(
        gbuf, wt_fc2, ROWS, DIM, HIDDEN, nullptr, out, out, bfc2);
}

// Round 5
// 345.507 us; speedup vs baseline: 1.3759x; 1.0115x over previous
//
#include <hip/hip_runtime.h>
#include <hip/hip_bf16.h>
#include <math.h>

#define DIM 768
#define NHEAD 12
#define HD 64
#define HIDDEN 384
#define BATCH 8
#define SEQ 1024
#define ROWS (BATCH*SEQ)
#define CHUNKB 4                 // batches per qkv/attn chunk
#define CHUNKR (CHUNKB*SEQ)      // 4096 rows

typedef short bf16x8 __attribute__((ext_vector_type(8)));
typedef float f32x4 __attribute__((ext_vector_type(4)));
typedef unsigned short u16;
typedef unsigned int u32;

__device__ __forceinline__ u16 f2bs(float f) {
    unsigned int u = __float_as_uint(f);
    unsigned int r = (u + 0x7FFFu + ((u >> 16) & 1u)) >> 16;
    return (u16)r;
}

// ---------------- tiled weight transpose: Wt[n][k] = bf16(W[k][n]) ----------------
__global__ __launch_bounds__(256) void wtrans(const float* __restrict__ W,
                                              u16* __restrict__ Wt, int K, int N) {
    __shared__ float tile[32][33];
    int n0 = blockIdx.x * 32, k0 = blockIdx.y * 32;
    int tx = threadIdx.x & 31, ty = threadIdx.x >> 5;  // ty 0..7
#pragma unroll
    for (int i = 0; i < 4; i++)
        tile[ty + i * 8][tx] = W[(long)(k0 + ty + i * 8) * N + n0 + tx];
    __syncthreads();
#pragma unroll
    for (int i = 0; i < 4; i++)
        Wt[(long)(n0 + ty + i * 8) * K + k0 + tx] = f2bs(tile[tx][ty + i * 8]);
}

// ---------------- layernorm: fp32 in -> bf16 out, one block per row ----------------
__global__ __launch_bounds__(256) void lnorm(const float* __restrict__ X,
                                             const float* __restrict__ w,
                                             const float* __restrict__ b,
                                             u16* __restrict__ Y) {
    int row = blockIdx.x;
    const float* xr = X + (long)row * DIM;
    int t = threadIdx.x;
    float v0 = xr[t], v1 = xr[t + 256], v2 = xr[t + 512];
    float s = v0 + v1 + v2;
    float s2 = v0 * v0 + v1 * v1 + v2 * v2;
    for (int off = 1; off < 64; off <<= 1) {
        s  += __shfl_xor(s,  off, 64);
        s2 += __shfl_xor(s2, off, 64);
    }
    __shared__ float ss[4], ss2[4];
    int wid = t >> 6;
    if ((t & 63) == 0) { ss[wid] = s; ss2[wid] = s2; }
    __syncthreads();
    s  = ss[0] + ss[1] + ss[2] + ss[3];
    s2 = ss2[0] + ss2[1] + ss2[2] + ss2[3];
    float mu = s * (1.0f / DIM);
    float var = s2 * (1.0f / DIM) - mu * mu;
    float rstd = rsqrtf(var + 1e-5f);
    u16* yr = Y + (long)row * DIM;
    yr[t]       = f2bs((v0 - mu) * rstd * w[t]       + b[t]);
    yr[t + 256] = f2bs((v1 - mu) * rstd * w[t + 256] + b[t + 256]);
    yr[t + 512] = f2bs((v2 - mu) * rstd * w[t + 512] + b[t + 512]);
}

// ---------------- bf16 MFMA GEMM, C = A[M,K] @ Bt[N,K]^T, BMxBNx64 tiles ----------------
// EPI: 0 = bf16 out; 1 = f32 out + resid; 2 = bf16 out + bias + exact GELU; 3 = f32 out + resid + bias
template <int BM, int BN, int EPI>
__global__ __launch_bounds__(256) void gemm_bt(const u16* __restrict__ A,
                                               const u16* __restrict__ Bt,
                                               int M, int N, int K,
                                               u16* __restrict__ Cb,
                                               float* __restrict__ Cf,
                                               const float* __restrict__ resid,
                                               const float* __restrict__ bias) {
    constexpr int MB = BM / 32, NB = BN / 32;
    __shared__ u16 As[BM * 72];
    __shared__ u16 Bs[BN * 72];
    int m0 = blockIdx.y * BM;
    int n0 = blockIdx.x * BN;
    int t = threadIdx.x;
    int lane = t & 63, w = t >> 6;
    int quad = lane >> 4, l16 = lane & 15;
    int wr = w >> 1, wc = w & 1;

    f32x4 acc[MB][NB];
#pragma unroll
    for (int mb = 0; mb < MB; mb++)
#pragma unroll
        for (int nb = 0; nb < NB; nb++) acc[mb][nb] = (f32x4){0.f, 0.f, 0.f, 0.f};

    for (int kt = 0; kt < K; kt += 64) {
        __syncthreads();
#pragma unroll
        for (int i = 0; i < BM / 32; i++) {
            int idx = t + i * 256;
            int row = idx >> 3, off = (idx & 7) * 8;
            *(bf16x8*)&As[row * 72 + off] = *(const bf16x8*)&A[(long)(m0 + row) * K + kt + off];
        }
#pragma unroll
        for (int i = 0; i < BN / 32; i++) {
            int idx = t + i * 256;
            int row = idx >> 3, off = (idx & 7) * 8;
            *(bf16x8*)&Bs[row * 72 + off] = *(const bf16x8*)&Bt[(long)(n0 + row) * K + kt + off];
        }
        __syncthreads();
#pragma unroll
        for (int kh = 0; kh < 2; kh++) {
            bf16x8 af[MB], bfr[NB];
#pragma unroll
            for (int mb = 0; mb < MB; mb++)
                af[mb] = *(const bf16x8*)&As[(wr * (BM / 2) + mb * 16 + l16) * 72 + kh * 32 + quad * 8];
#pragma unroll
            for (int nb = 0; nb < NB; nb++)
                bfr[nb] = *(const bf16x8*)&Bs[(wc * (BN / 2) + nb * 16 + l16) * 72 + kh * 32 + quad * 8];
#pragma unroll
            for (int mb = 0; mb < MB; mb++)
#pragma unroll
                for (int nb = 0; nb < NB; nb++)
                    acc[mb][nb] = __builtin_amdgcn_mfma_f32_16x16x32_bf16(af[mb], bfr[nb], acc[mb][nb], 0, 0, 0);
        }
    }

    int mbase = m0 + wr * (BM / 2), nbase = n0 + wc * (BN / 2);
#pragma unroll
    for (int mb = 0; mb < MB; mb++)
#pragma unroll
        for (int nb = 0; nb < NB; nb++) {
            int r0 = mbase + mb * 16 + quad * 4;
            int c = nbase + nb * 16 + l16;
#pragma unroll
            for (int r = 0; r < 4; r++) {
                float v = acc[mb][nb][r];
                long idx = (long)(r0 + r) * N + c;
                if (EPI == 0) {
                    Cb[idx] = f2bs(v);
                } else if (EPI == 1) {
                    Cf[idx] = resid[idx] + v;
                } else if (EPI == 2) {
                    float xg = v + bias[c];
                    Cb[idx] = f2bs(xg * 0.5f * (1.0f + erff(xg * 0.70710678118f)));
                } else {
                    Cf[idx] = resid[idx] + v + bias[c];
                }
            }
        }
}

// ---------------- flash attention: one block per (qtile=64, head, local-batch) ----------------
// QKV bf16 [nb*S, 3*DIM]; Q at col h*64, K at 768+h*64, V at 1536+h*64. softmax over 8*logits.
// KT=128 keys per iteration.
__global__ __launch_bounds__(256) void attn(const u16* __restrict__ QKV, u16* __restrict__ O) {
    __shared__ u16 Ks[128 * 72];      // K rows [kv][d], stride 72
    __shared__ u16 Vs[64 * 136];      // transposed: Vs[d][kv], stride 136
    __shared__ u16 Ps[4][16 * 136];   // per-wave P tile [m][kv] (wave-private), stride 136
    int q0 = blockIdx.x * 64;
    int h = blockIdx.y;
    int b = blockIdx.z;
    int t = threadIdx.x;
    int lane = t & 63, w = t >> 6;
    int quad = lane >> 4, l16 = lane & 15;

    const long rs = 3 * DIM;  // 2304
    const u16* base = QKV + (long)b * SEQ * rs;

    int qrow = q0 + w * 16 + l16;
    bf16x8 qf0 = *(const bf16x8*)&base[(long)qrow * rs + h * 64 + quad * 8];
    bf16x8 qf1 = *(const bf16x8*)&base[(long)qrow * rs + h * 64 + 32 + quad * 8];

    f32x4 o[4];
#pragma unroll
    for (int jb = 0; jb < 4; jb++) o[jb] = (f32x4){0.f, 0.f, 0.f, 0.f};
    float m_run[4], l_run[4];
#pragma unroll
    for (int r = 0; r < 4; r++) { m_run[r] = -1e30f; l_run[r] = 0.f; }

    const float L2E8 = 11.54156032f;  // 8 * log2(e); softmax over 8*s via exp2

    // staging decomposition: K: row kv=t>>1, 32-elem half (t&1)*32 (full coverage!);
    // V: pair p=t&63, d-block vo=t>>6
    int kvr = t >> 1, khalf = (t & 1) * 32;
    int vp = t & 63, vo = t >> 6;

    for (int kt = 0; kt < SEQ; kt += 128) {
        __syncthreads();
        {
            const u16* kr = &base[(long)(kt + kvr) * rs + DIM + h * 64 + khalf];
            *(bf16x8*)&Ks[kvr * 72 + khalf]      = *(const bf16x8*)&kr[0];
            *(bf16x8*)&Ks[kvr * 72 + khalf + 8]  = *(const bf16x8*)&kr[8];
            *(bf16x8*)&Ks[kvr * 72 + khalf + 16] = *(const bf16x8*)&kr[16];
            *(bf16x8*)&Ks[kvr * 72 + khalf + 24] = *(const bf16x8*)&kr[24];
            // V: two rows (2p, 2p+1), 16 d-values each, packed kv-pairs -> b32 LDS writes
            const u16* v0r = &base[(long)(kt + 2 * vp) * rs + 2 * DIM + h * 64 + vo * 16];
            const u16* v1r = v0r + rs;
            bf16x8 va0 = *(const bf16x8*)&v0r[0];
            bf16x8 va1 = *(const bf16x8*)&v0r[8];
            bf16x8 vb0 = *(const bf16x8*)&v1r[0];
            bf16x8 vb1 = *(const bf16x8*)&v1r[8];
#pragma unroll
            for (int j = 0; j < 8; j++) {
                u32 pk = (u32)(u16)va0[j] | ((u32)(u16)vb0[j] << 16);
                *(u32*)&Vs[(vo * 16 + j) * 136 + 2 * vp] = pk;
            }
#pragma unroll
            for (int j = 0; j < 8; j++) {
                u32 pk = (u32)(u16)va1[j] | ((u32)(u16)vb1[j] << 16);
                *(u32*)&Vs[(vo * 16 + 8 + j) * 136 + 2 * vp] = pk;
            }
        }
        __syncthreads();

        f32x4 s[8];
#pragma unroll
        for (int jb = 0; jb < 8; jb++) {
            bf16x8 kf0 = *(const bf16x8*)&Ks[(jb * 16 + l16) * 72 + quad * 8];
            bf16x8 kf1 = *(const bf16x8*)&Ks[(jb * 16 + l16) * 72 + 32 + quad * 8];
            f32x4 z = (f32x4){0.f, 0.f, 0.f, 0.f};
            z = __builtin_amdgcn_mfma_f32_16x16x32_bf16(qf0, kf0, z, 0, 0, 0);
            z = __builtin_amdgcn_mfma_f32_16x16x32_bf16(qf1, kf1, z, 0, 0, 0);
            s[jb] = z;
        }

        // online softmax over 8*s (all exp in base-2 with folded scale)
#pragma unroll
        for (int r = 0; r < 4; r++) {
            float m1 = s[0][r];
#pragma unroll
            for (int jb = 1; jb < 8; jb++) m1 = fmaxf(m1, s[jb][r]);
            for (int off = 1; off < 16; off <<= 1) m1 = fmaxf(m1, __shfl_xor(m1, off, 64));
            float mn = fmaxf(m_run[r], m1);
            float alpha = exp2f((m_run[r] - mn) * L2E8);
            m_run[r] = mn;
            float mn8 = mn * L2E8;
            float rsum = 0.f;
#pragma unroll
            for (int jb = 0; jb < 8; jb++) {
                float p = exp2f(fmaf(s[jb][r], L2E8, -mn8));
                s[jb][r] = p;
                rsum += p;
            }
            for (int off = 1; off < 16; off <<= 1) rsum += __shfl_xor(rsum, off, 64);
            l_run[r] = l_run[r] * alpha + rsum;
#pragma unroll
            for (int jb = 0; jb < 4; jb++) o[jb][r] *= alpha;
        }

        // P -> LDS (wave-private; same-wave lgkm ordering, no barrier needed)
#pragma unroll
        for (int jb = 0; jb < 8; jb++)
#pragma unroll
            for (int r = 0; r < 4; r++)
                Ps[w][(quad * 4 + r) * 136 + jb * 16 + l16] = f2bs(s[jb][r]);

#pragma unroll
        for (int c = 0; c < 4; c++) {
            bf16x8 pf = *(const bf16x8*)&Ps[w][l16 * 136 + c * 32 + quad * 8];
#pragma unroll
            for (int jb = 0; jb < 4; jb++) {
                bf16x8 vf = *(const bf16x8*)&Vs[(jb * 16 + l16) * 136 + c * 32 + quad * 8];
                o[jb] = __builtin_amdgcn_mfma_f32_16x16x32_bf16(pf, vf, o[jb], 0, 0, 0);
            }
        }
    }

    u16* orow = O + ((long)(b * SEQ + q0 + w * 16)) * DIM + h * 64;
#pragma unroll
    for (int jb = 0; jb < 4; jb++)
#pragma unroll
        for (int r = 0; r < 4; r++) {
            float v = o[jb][r] / l_run[r];
            orow[(long)(quad * 4 + r) * DIM + jb * 16 + l16] = f2bs(v);
        }
}

extern "C" void kernel_launch(void* const* d_in, const int* in_sizes, int n_in,
                              void* d_out, int out_size, void* d_ws, size_t ws_size,
                              hipStream_t stream) {
    const float* x     = (const float*)d_in[0];
    const float* ln1w  = (const float*)d_in[1];
    const float* ln1b  = (const float*)d_in[2];
    const float* ln2w  = (const float*)d_in[3];
    const float* ln2b  = (const float*)d_in[4];
    const float* wqkv  = (const float*)d_in[5];
    const float* wproj = (const float*)d_in[6];
    const float* wfc1  = (const float*)d_in[7];
    const float* bfc1  = (const float*)d_in[8];
    const float* wfc2  = (const float*)d_in[9];
    const float* bfc2  = (const float*)d_in[10];
    float* out = (float*)d_out;

    // ---- ws layout: 24.8 MB total (proven-safe; ws overflow corrupts harness state).
    // d_out (25.2 MB fp32) doubles as the qkv chunk buffer (18.9 MB bf16) until proj.
    char* ws = (char*)d_ws;
    size_t off = 0;
    auto alloc = [&](size_t bytes) {
        void* p = ws + off;
        off = (off + bytes + 255) & ~(size_t)255;
        return p;
    };
    u16* wt_qkv  = (u16*)alloc((size_t)3 * DIM * DIM * 2);   // 3.54 MB
    u16* wt_proj = (u16*)alloc((size_t)DIM * DIM * 2);       // 1.18 MB
    u16* wt_fc1  = (u16*)alloc((size_t)HIDDEN * DIM * 2);    // 0.59 MB
    u16* wt_fc2  = (u16*)alloc((size_t)DIM * HIDDEN * 2);    // 0.59 MB
    u16* hbuf    = (u16*)alloc((size_t)ROWS * DIM * 2);      // 12.58 MB: ln1 out -> attn out -> ln2 out
    u16* gbuf    = (u16*)alloc((size_t)ROWS * HIDDEN * 2);   // 6.29 MB: gelu out
    u16* qd      = (u16*)d_out;                              // qkv chunk (bf16) lives in d_out

    // 1. weights -> bf16 transposed (tiled, coalesced)
    wtrans<<<dim3(3 * DIM / 32, DIM / 32), 256, 0, stream>>>(wqkv, wt_qkv, DIM, 3 * DIM);
    wtrans<<<dim3(DIM / 32, DIM / 32), 256, 0, stream>>>(wproj, wt_proj, DIM, DIM);
    wtrans<<<dim3(HIDDEN / 32, DIM / 32), 256, 0, stream>>>(wfc1, wt_fc1, DIM, HIDDEN);
    wtrans<<<dim3(DIM / 32, HIDDEN / 32), 256, 0, stream>>>(wfc2, wt_fc2, HIDDEN, DIM);

    // 2. ln1: hbuf = LN(x)
    lnorm<<<ROWS, 256, 0, stream>>>(x, ln1w, ln1b, hbuf);

    // 3. per-chunk (4 batches): qkv GEMM into d_out, attn writes O back into hbuf
    for (int c = 0; c < ROWS / CHUNKR; c++) {
        const u16* hA = hbuf + (size_t)c * CHUNKR * DIM;
        gemm_bt<128, 128, 0><<<dim3(3 * DIM / 128, CHUNKR / 128), 256, 0, stream>>>(
            hA, wt_qkv, CHUNKR, 3 * DIM, DIM, qd, nullptr, nullptr, nullptr);
        attn<<<dim3(SEQ / 64, NHEAD, CHUNKB), 256, 0, stream>>>(
            qd, hbuf + (size_t)c * CHUNKR * DIM);
    }

    // 4. x1 = x + attn_out @ w_proj  (fp32 into d_out; qkv chunk dead)
    gemm_bt<128, 64, 1><<<dim3(DIM / 64, ROWS / 128), 256, 0, stream>>>(
        hbuf, wt_proj, ROWS, DIM, DIM, nullptr, out, x, nullptr);

    // 5. ln2: hbuf = LN(x1)
    lnorm<<<ROWS, 256, 0, stream>>>(out, ln2w, ln2b, hbuf);

    // 6. g = gelu(hbuf @ w_fc1 + b_fc1)  (bf16 into gbuf)
    gemm_bt<64, 64, 2><<<dim3(HIDDEN / 64, ROWS / 64), 256, 0, stream>>>(
        hbuf, wt_fc1, ROWS, HIDDEN, DIM, gbuf, nullptr, nullptr, bfc1);

    // 7. out = x1 + g @ w_fc2 + b_fc2  (fp32, in-place over x1)
    gemm_bt<128, 64, 3><<<dim3(DIM / 64, ROWS / 128), 256, 0, stream>>>(
        gbuf, wt_fc2, ROWS, DIM, HIDDEN, nullptr, out, out, bfc2);
}

// Round 6
// 323.171 us; speedup vs baseline: 1.4710x; 1.0691x over previous
//
#include <hip/hip_runtime.h>
#include <hip/hip_bf16.h>
#include <math.h>

#define DIM 768
#define NHEAD 12
#define HD 64
#define HIDDEN 384
#define BATCH 8
#define SEQ 1024
#define ROWS (BATCH*SEQ)
#define CHUNKB 4                 // batches per qkv/attn chunk (fallback path)
#define CHUNKR (CHUNKB*SEQ)

typedef short bf16x8 __attribute__((ext_vector_type(8)));
typedef float f32x4 __attribute__((ext_vector_type(4)));
typedef unsigned short u16;
typedef unsigned int u32;

__device__ __forceinline__ u16 f2bs(float f) {
    unsigned int u = __float_as_uint(f);
    unsigned int r = (u + 0x7FFFu + ((u >> 16) & 1u)) >> 16;
    return (u16)r;
}

// HW packed bf16 convert (v_cvt_pk_bf16_f32 on gfx950), RNE — same rounding as f2bs
__device__ __forceinline__ u32 packbf2(float a, float b) {
    __hip_bfloat162 h = __float22bfloat162_rn(make_float2(a, b));
    u32 r;
    __builtin_memcpy(&r, &h, 4);
    return r;
}

// ---------------- tiled weight transpose: Wt[n][k] = bf16(W[k][n]) ----------------
__global__ __launch_bounds__(256) void wtrans(const float* __restrict__ W,
                                              u16* __restrict__ Wt, int K, int N) {
    __shared__ float tile[32][33];
    int n0 = blockIdx.x * 32, k0 = blockIdx.y * 32;
    int tx = threadIdx.x & 31, ty = threadIdx.x >> 5;
#pragma unroll
    for (int i = 0; i < 4; i++)
        tile[ty + i * 8][tx] = W[(long)(k0 + ty + i * 8) * N + n0 + tx];
    __syncthreads();
#pragma unroll
    for (int i = 0; i < 4; i++)
        Wt[(long)(n0 + ty + i * 8) * K + k0 + tx] = f2bs(tile[tx][ty + i * 8]);
}

// ---------------- layernorm: fp32 in -> bf16 out, one block per row ----------------
__global__ __launch_bounds__(256) void lnorm(const float* __restrict__ X,
                                             const float* __restrict__ w,
                                             const float* __restrict__ b,
                                             u16* __restrict__ Y) {
    int row = blockIdx.x;
    const float* xr = X + (long)row * DIM;
    int t = threadIdx.x;
    float v0 = xr[t], v1 = xr[t + 256], v2 = xr[t + 512];
    float s = v0 + v1 + v2;
    float s2 = v0 * v0 + v1 * v1 + v2 * v2;
    for (int off = 1; off < 64; off <<= 1) {
        s  += __shfl_xor(s,  off, 64);
        s2 += __shfl_xor(s2, off, 64);
    }
    __shared__ float ss[4], ss2[4];
    int wid = t >> 6;
    if ((t & 63) == 0) { ss[wid] = s; ss2[wid] = s2; }
    __syncthreads();
    s  = ss[0] + ss[1] + ss[2] + ss[3];
    s2 = ss2[0] + ss2[1] + ss2[2] + ss2[3];
    float mu = s * (1.0f / DIM);
    float var = s2 * (1.0f / DIM) - mu * mu;
    float rstd = rsqrtf(var + 1e-5f);
    u16* yr = Y + (long)row * DIM;
    yr[t]       = f2bs((v0 - mu) * rstd * w[t]       + b[t]);
    yr[t + 256] = f2bs((v1 - mu) * rstd * w[t + 256] + b[t + 256]);
    yr[t + 512] = f2bs((v2 - mu) * rstd * w[t + 512] + b[t + 512]);
}

// ---------------- bf16 MFMA GEMM, C = A[M,K] @ Bt[N,K]^T, BMxBNx64 tiles ----------------
// EPI: 0 = bf16 out; 1 = f32 out + resid; 2 = bf16 out + bias + exact GELU; 3 = f32 out + resid + bias
template <int BM, int BN, int EPI>
__global__ __launch_bounds__(256) void gemm_bt(const u16* __restrict__ A,
                                               const u16* __restrict__ Bt,
                                               int M, int N, int K,
                                               u16* __restrict__ Cb,
                                               float* __restrict__ Cf,
                                               const float* __restrict__ resid,
                                               const float* __restrict__ bias) {
    constexpr int MB = BM / 32, NB = BN / 32;
    __shared__ u16 As[BM * 72];
    __shared__ u16 Bs[BN * 72];
    int m0 = blockIdx.y * BM;
    int n0 = blockIdx.x * BN;
    int t = threadIdx.x;
    int lane = t & 63, w = t >> 6;
    int quad = lane >> 4, l16 = lane & 15;
    int wr = w >> 1, wc = w & 1;

    f32x4 acc[MB][NB];
#pragma unroll
    for (int mb = 0; mb < MB; mb++)
#pragma unroll
        for (int nb = 0; nb < NB; nb++) acc[mb][nb] = (f32x4){0.f, 0.f, 0.f, 0.f};

    for (int kt = 0; kt < K; kt += 64) {
        __syncthreads();
#pragma unroll
        for (int i = 0; i < BM / 32; i++) {
            int idx = t + i * 256;
            int row = idx >> 3, off = (idx & 7) * 8;
            *(bf16x8*)&As[row * 72 + off] = *(const bf16x8*)&A[(long)(m0 + row) * K + kt + off];
        }
#pragma unroll
        for (int i = 0; i < BN / 32; i++) {
            int idx = t + i * 256;
            int row = idx >> 3, off = (idx & 7) * 8;
            *(bf16x8*)&Bs[row * 72 + off] = *(const bf16x8*)&Bt[(long)(n0 + row) * K + kt + off];
        }
        __syncthreads();
#pragma unroll
        for (int kh = 0; kh < 2; kh++) {
            bf16x8 af[MB], bfr[NB];
#pragma unroll
            for (int mb = 0; mb < MB; mb++)
                af[mb] = *(const bf16x8*)&As[(wr * (BM / 2) + mb * 16 + l16) * 72 + kh * 32 + quad * 8];
#pragma unroll
            for (int nb = 0; nb < NB; nb++)
                bfr[nb] = *(const bf16x8*)&Bs[(wc * (BN / 2) + nb * 16 + l16) * 72 + kh * 32 + quad * 8];
#pragma unroll
            for (int mb = 0; mb < MB; mb++)
#pragma unroll
                for (int nb = 0; nb < NB; nb++)
                    acc[mb][nb] = __builtin_amdgcn_mfma_f32_16x16x32_bf16(af[mb], bfr[nb], acc[mb][nb], 0, 0, 0);
        }
    }

    int mbase = m0 + wr * (BM / 2), nbase = n0 + wc * (BN / 2);
#pragma unroll
    for (int mb = 0; mb < MB; mb++)
#pragma unroll
        for (int nb = 0; nb < NB; nb++) {
            int r0 = mbase + mb * 16 + quad * 4;
            int c = nbase + nb * 16 + l16;
#pragma unroll
            for (int r = 0; r < 4; r++) {
                float v = acc[mb][nb][r];
                long idx = (long)(r0 + r) * N + c;
                if (EPI == 0) {
                    Cb[idx] = f2bs(v);
                } else if (EPI == 1) {
                    Cf[idx] = resid[idx] + v;
                } else if (EPI == 2) {
                    float xg = v + bias[c];
                    Cb[idx] = f2bs(xg * 0.5f * (1.0f + erff(xg * 0.70710678118f)));
                } else {
                    Cf[idx] = resid[idx] + v + bias[c];
                }
            }
        }
}

// ---------------- flash attention: QT=128 q-rows/block, KT=128 keys/iter ----------------
// One block per (qtile=128, head, batch). Each wave: 32 q-rows as 2 row-groups of 16.
// Register-prefetch pipeline for next K/V tile. softmax over 8*logits (base-2, folded).
__global__ __launch_bounds__(256, 3) void attn(const u16* __restrict__ QKV, u16* __restrict__ O) {
    __shared__ u16 Ks[128 * 72];      // K rows [kv][d], stride 72
    __shared__ u16 Vs[64 * 136];      // transposed: Vs[d][kv], stride 136
    __shared__ u16 Ps[4][16 * 136];   // per-wave P tile [m][kv] (wave-private), stride 136
    int q0 = blockIdx.x * 128;
    int h = blockIdx.y;
    int b = blockIdx.z;
    int t = threadIdx.x;
    int lane = t & 63, w = t >> 6;
    int quad = lane >> 4, l16 = lane & 15;

    const long rs = 3 * DIM;  // 2304
    const u16* base = QKV + (long)b * SEQ * rs;

    bf16x8 qf[2][2];
#pragma unroll
    for (int rg = 0; rg < 2; rg++) {
        int qrow = q0 + w * 32 + rg * 16 + l16;
        qf[rg][0] = *(const bf16x8*)&base[(long)qrow * rs + h * 64 + quad * 8];
        qf[rg][1] = *(const bf16x8*)&base[(long)qrow * rs + h * 64 + 32 + quad * 8];
    }

    f32x4 o[2][4];
    float m_run[2][4], l_run[2][4];
#pragma unroll
    for (int rg = 0; rg < 2; rg++)
#pragma unroll
        for (int jb = 0; jb < 4; jb++) {
            o[rg][jb] = (f32x4){0.f, 0.f, 0.f, 0.f};
            m_run[rg][jb] = -1e30f;
            l_run[rg][jb] = 0.f;
        }

    const float L2E8 = 11.54156032f;  // 8 * log2(e)

    // staging decomposition: K: row kv=t>>1, 32-elem half (t&1)*32; V: pair vp=t&63, d-block vo=t>>6
    int kvr = t >> 1, khalf = (t & 1) * 32;
    int vp = t & 63, vo = t >> 6;

    const u16* kptr = &base[(long)kvr * rs + DIM + h * 64 + khalf];
    const u16* vptr = &base[(long)(2 * vp) * rs + 2 * DIM + h * 64 + vo * 16];
    const long kstep = (long)128 * rs;

    bf16x8 kpre[4], va0, va1, vb0, vb1;
    // prefetch tile 0
    kpre[0] = *(const bf16x8*)&kptr[0];
    kpre[1] = *(const bf16x8*)&kptr[8];
    kpre[2] = *(const bf16x8*)&kptr[16];
    kpre[3] = *(const bf16x8*)&kptr[24];
    va0 = *(const bf16x8*)&vptr[0];
    va1 = *(const bf16x8*)&vptr[8];
    vb0 = *(const bf16x8*)&vptr[rs];
    vb1 = *(const bf16x8*)&vptr[rs + 8];

    for (int kt = 0; kt < SEQ; kt += 128) {
        __syncthreads();
        {
            *(bf16x8*)&Ks[kvr * 72 + khalf]      = kpre[0];
            *(bf16x8*)&Ks[kvr * 72 + khalf + 8]  = kpre[1];
            *(bf16x8*)&Ks[kvr * 72 + khalf + 16] = kpre[2];
            *(bf16x8*)&Ks[kvr * 72 + khalf + 24] = kpre[3];
#pragma unroll
            for (int j = 0; j < 8; j++) {
                u32 pk = (u32)(u16)va0[j] | ((u32)(u16)vb0[j] << 16);
                *(u32*)&Vs[(vo * 16 + j) * 136 + 2 * vp] = pk;
            }
#pragma unroll
            for (int j = 0; j < 8; j++) {
                u32 pk = (u32)(u16)va1[j] | ((u32)(u16)vb1[j] << 16);
                *(u32*)&Vs[(vo * 16 + 8 + j) * 136 + 2 * vp] = pk;
            }
        }
        __syncthreads();

        // issue next tile's global loads now; latency hidden by compute below
        if (kt + 128 < SEQ) {
            kptr += kstep; vptr += kstep;
            kpre[0] = *(const bf16x8*)&kptr[0];
            kpre[1] = *(const bf16x8*)&kptr[8];
            kpre[2] = *(const bf16x8*)&kptr[16];
            kpre[3] = *(const bf16x8*)&kptr[24];
            va0 = *(const bf16x8*)&vptr[0];
            va1 = *(const bf16x8*)&vptr[8];
            vb0 = *(const bf16x8*)&vptr[rs];
            vb1 = *(const bf16x8*)&vptr[rs + 8];
        }

#pragma unroll
        for (int rg = 0; rg < 2; rg++) {
            f32x4 s[8];
#pragma unroll
            for (int jb = 0; jb < 8; jb++) {
                bf16x8 kf0 = *(const bf16x8*)&Ks[(jb * 16 + l16) * 72 + quad * 8];
                bf16x8 kf1 = *(const bf16x8*)&Ks[(jb * 16 + l16) * 72 + 32 + quad * 8];
                f32x4 z = (f32x4){0.f, 0.f, 0.f, 0.f};
                z = __builtin_amdgcn_mfma_f32_16x16x32_bf16(qf[rg][0], kf0, z, 0, 0, 0);
                z = __builtin_amdgcn_mfma_f32_16x16x32_bf16(qf[rg][1], kf1, z, 0, 0, 0);
                s[jb] = z;
            }

#pragma unroll
            for (int r = 0; r < 4; r++) {
                float m1 = s[0][r];
#pragma unroll
                for (int jb = 1; jb < 8; jb++) m1 = fmaxf(m1, s[jb][r]);
                for (int off = 1; off < 16; off <<= 1) m1 = fmaxf(m1, __shfl_xor(m1, off, 64));
                float mn = fmaxf(m_run[rg][r], m1);
                float alpha = exp2f((m_run[rg][r] - mn) * L2E8);
                m_run[rg][r] = mn;
                float mn8 = mn * L2E8;
                float rsum = 0.f;
#pragma unroll
                for (int jb = 0; jb < 8; jb++) {
                    float p = exp2f(fmaf(s[jb][r], L2E8, -mn8));
                    s[jb][r] = p;
                    rsum += p;
                }
                for (int off = 1; off < 16; off <<= 1) rsum += __shfl_xor(rsum, off, 64);
                l_run[rg][r] = l_run[rg][r] * alpha + rsum;
#pragma unroll
                for (int jb = 0; jb < 4; jb++) o[rg][jb][r] *= alpha;
            }

            // P -> LDS via packed HW cvt (wave-private; same-wave lgkm ordering)
#pragma unroll
            for (int jb = 0; jb < 8; jb++) {
                u32 p01 = packbf2(s[jb][0], s[jb][1]);
                u32 p23 = packbf2(s[jb][2], s[jb][3]);
                int cidx = jb * 16 + l16;
                Ps[w][(quad * 4 + 0) * 136 + cidx] = (u16)p01;
                Ps[w][(quad * 4 + 1) * 136 + cidx] = (u16)(p01 >> 16);
                Ps[w][(quad * 4 + 2) * 136 + cidx] = (u16)p23;
                Ps[w][(quad * 4 + 3) * 136 + cidx] = (u16)(p23 >> 16);
            }

#pragma unroll
            for (int c = 0; c < 4; c++) {
                bf16x8 pf = *(const bf16x8*)&Ps[w][l16 * 136 + c * 32 + quad * 8];
#pragma unroll
                for (int jb = 0; jb < 4; jb++) {
                    bf16x8 vf = *(const bf16x8*)&Vs[(jb * 16 + l16) * 136 + c * 32 + quad * 8];
                    o[rg][jb] = __builtin_amdgcn_mfma_f32_16x16x32_bf16(pf, vf, o[rg][jb], 0, 0, 0);
                }
            }
        }
    }

#pragma unroll
    for (int rg = 0; rg < 2; rg++) {
        u16* orow = O + ((long)(b * SEQ + q0 + w * 32 + rg * 16)) * DIM + h * 64;
#pragma unroll
        for (int jb = 0; jb < 4; jb++) {
            float i0 = o[rg][jb][0] / l_run[rg][0];
            float i1 = o[rg][jb][1] / l_run[rg][1];
            float i2 = o[rg][jb][2] / l_run[rg][2];
            float i3 = o[rg][jb][3] / l_run[rg][3];
            u32 p01 = packbf2(i0, i1), p23 = packbf2(i2, i3);
            int cidx = jb * 16 + l16;
            orow[(long)(quad * 4 + 0) * DIM + cidx] = (u16)p01;
            orow[(long)(quad * 4 + 1) * DIM + cidx] = (u16)(p01 >> 16);
            orow[(long)(quad * 4 + 2) * DIM + cidx] = (u16)p23;
            orow[(long)(quad * 4 + 3) * DIM + cidx] = (u16)(p23 >> 16);
        }
    }
}

extern "C" void kernel_launch(void* const* d_in, const int* in_sizes, int n_in,
                              void* d_out, int out_size, void* d_ws, size_t ws_size,
                              hipStream_t stream) {
    const float* x     = (const float*)d_in[0];
    const float* ln1w  = (const float*)d_in[1];
    const float* ln1b  = (const float*)d_in[2];
    const float* ln2w  = (const float*)d_in[3];
    const float* ln2b  = (const float*)d_in[4];
    const float* wqkv  = (const float*)d_in[5];
    const float* wproj = (const float*)d_in[6];
    const float* wfc1  = (const float*)d_in[7];
    const float* bfc1  = (const float*)d_in[8];
    const float* wfc2  = (const float*)d_in[9];
    const float* bfc2  = (const float*)d_in[10];
    float* out = (float*)d_out;

    // ---- workspace (ws overflow corrupts harness state -> runtime-check before using
    // the full-QKV layout; fallback stays within the proven ~25 MB footprint).
    char* ws = (char*)d_ws;
    size_t off = 0;
    auto alloc = [&](size_t bytes) {
        void* p = ws + off;
        off = (off + bytes + 255) & ~(size_t)255;
        return p;
    };
    u16* wt_qkv  = (u16*)alloc((size_t)3 * DIM * DIM * 2);
    u16* wt_proj = (u16*)alloc((size_t)DIM * DIM * 2);
    u16* wt_fc1  = (u16*)alloc((size_t)HIDDEN * DIM * 2);
    u16* wt_fc2  = (u16*)alloc((size_t)DIM * HIDDEN * 2);
    u16* hbuf    = (u16*)alloc((size_t)ROWS * DIM * 2);      // ln1 out -> attn out -> ln2 out
    u16* gbuf    = (u16*)alloc((size_t)ROWS * HIDDEN * 2);   // gelu out
    size_t qkv_bytes = (size_t)ROWS * 3 * DIM * 2;           // 37.75 MB
    u16* qkvfull = (off + qkv_bytes + 1024 <= ws_size) ? (u16*)alloc(qkv_bytes) : nullptr;

    // 1. weights -> bf16 transposed
    wtrans<<<dim3(3 * DIM / 32, DIM / 32), 256, 0, stream>>>(wqkv, wt_qkv, DIM, 3 * DIM);
    wtrans<<<dim3(DIM / 32, DIM / 32), 256, 0, stream>>>(wproj, wt_proj, DIM, DIM);
    wtrans<<<dim3(HIDDEN / 32, DIM / 32), 256, 0, stream>>>(wfc1, wt_fc1, DIM, HIDDEN);
    wtrans<<<dim3(DIM / 32, HIDDEN / 32), 256, 0, stream>>>(wfc2, wt_fc2, HIDDEN, DIM);

    // 2. ln1
    lnorm<<<ROWS, 256, 0, stream>>>(x, ln1w, ln1b, hbuf);

    // 3. qkv + attention
    if (qkvfull) {
        gemm_bt<128, 128, 0><<<dim3(3 * DIM / 128, ROWS / 128), 256, 0, stream>>>(
            hbuf, wt_qkv, ROWS, 3 * DIM, DIM, qkvfull, nullptr, nullptr, nullptr);
        attn<<<dim3(SEQ / 128, NHEAD, BATCH), 256, 0, stream>>>(qkvfull, hbuf);
    } else {
        u16* qd = (u16*)d_out;  // qkv chunk lives in d_out until proj
        for (int c = 0; c < ROWS / CHUNKR; c++) {
            const u16* hA = hbuf + (size_t)c * CHUNKR * DIM;
            gemm_bt<128, 128, 0><<<dim3(3 * DIM / 128, CHUNKR / 128), 256, 0, stream>>>(
                hA, wt_qkv, CHUNKR, 3 * DIM, DIM, qd, nullptr, nullptr, nullptr);
            attn<<<dim3(SEQ / 128, NHEAD, CHUNKB), 256, 0, stream>>>(
                qd, hbuf + (size_t)c * CHUNKR * DIM);
        }
    }

    // 4. x1 = x + attn_out @ w_proj  (fp32 into d_out)
    gemm_bt<128, 64, 1><<<dim3(DIM / 64, ROWS / 128), 256, 0, stream>>>(
        hbuf, wt_proj, ROWS, DIM, DIM, nullptr, out, x, nullptr);

    // 5. ln2
    lnorm<<<ROWS, 256, 0, stream>>>(out, ln2w, ln2b, hbuf);

    // 6. g = gelu(hbuf @ w_fc1 + b_fc1)
    gemm_bt<64, 64, 2><<<dim3(HIDDEN / 64, ROWS / 64), 256, 0, stream>>>(
        hbuf, wt_fc1, ROWS, HIDDEN, DIM, gbuf, nullptr, nullptr, bfc1);

    // 7. out = x1 + g @ w_fc2 + b_fc2  (fp32, in-place over x1)
    gemm_bt<128, 64, 3><<<dim3(DIM / 64, ROWS / 128), 256, 0, stream>>>(
        gbuf, wt_fc2, ROWS, DIM, HIDDEN, nullptr, out, out, bfc2);
}

// Round 7
// 280.487 us; speedup vs baseline: 1.6949x; 1.1522x over previous
//
#include <hip/hip_runtime.h>
#include <hip/hip_bf16.h>
#include <math.h>

#define DIM 768
#define NHEAD 12
#define HD 64
#define HIDDEN 384
#define BATCH 8
#define SEQ 1024
#define ROWS (BATCH*SEQ)
#define CHUNKB 4                 // batches per qkv/attn chunk (fallback path)
#define CHUNKR (CHUNKB*SEQ)

typedef short bf16x8 __attribute__((ext_vector_type(8)));
typedef float f32x4 __attribute__((ext_vector_type(4)));
typedef unsigned int u32x2 __attribute__((ext_vector_type(2)));
typedef unsigned short u16;
typedef unsigned int u32;

__device__ __forceinline__ u16 f2bs(float f) {
    unsigned int u = __float_as_uint(f);
    unsigned int r = (u + 0x7FFFu + ((u >> 16) & 1u)) >> 16;
    return (u16)r;
}

// HW packed bf16 convert (v_cvt_pk_bf16_f32 on gfx950), RNE
__device__ __forceinline__ u32 packbf2(float a, float b) {
    __hip_bfloat162 h = __float22bfloat162_rn(make_float2(a, b));
    u32 r;
    __builtin_memcpy(&r, &h, 4);
    return r;
}

// async global->LDS DMA, 16 B/lane; LDS dest = wave-uniform base + lane*16
__device__ __forceinline__ void gld16(const u16* g, u16* l) {
    __builtin_amdgcn_global_load_lds(
        (const __attribute__((address_space(1))) unsigned int*)g,
        (__attribute__((address_space(3))) unsigned int*)l, 16, 0, 0);
}

// ---------------- tiled weight transpose: Wt[n][k] = bf16(W[k][n]) ----------------
__global__ __launch_bounds__(256) void wtrans(const float* __restrict__ W,
                                              u16* __restrict__ Wt, int K, int N) {
    __shared__ float tile[32][33];
    int n0 = blockIdx.x * 32, k0 = blockIdx.y * 32;
    int tx = threadIdx.x & 31, ty = threadIdx.x >> 5;
#pragma unroll
    for (int i = 0; i < 4; i++)
        tile[ty + i * 8][tx] = W[(long)(k0 + ty + i * 8) * N + n0 + tx];
    __syncthreads();
#pragma unroll
    for (int i = 0; i < 4; i++)
        Wt[(long)(n0 + ty + i * 8) * K + k0 + tx] = f2bs(tile[tx][ty + i * 8]);
}

// ---------------- layernorm: fp32 in -> bf16 out, one block per row ----------------
__global__ __launch_bounds__(256) void lnorm(const float* __restrict__ X,
                                             const float* __restrict__ w,
                                             const float* __restrict__ b,
                                             u16* __restrict__ Y) {
    int row = blockIdx.x;
    const float* xr = X + (long)row * DIM;
    int t = threadIdx.x;
    float v0 = xr[t], v1 = xr[t + 256], v2 = xr[t + 512];
    float s = v0 + v1 + v2;
    float s2 = v0 * v0 + v1 * v1 + v2 * v2;
    for (int off = 1; off < 64; off <<= 1) {
        s  += __shfl_xor(s,  off, 64);
        s2 += __shfl_xor(s2, off, 64);
    }
    __shared__ float ss[4], ss2[4];
    int wid = t >> 6;
    if ((t & 63) == 0) { ss[wid] = s; ss2[wid] = s2; }
    __syncthreads();
    s  = ss[0] + ss[1] + ss[2] + ss[3];
    s2 = ss2[0] + ss2[1] + ss2[2] + ss2[3];
    float mu = s * (1.0f / DIM);
    float var = s2 * (1.0f / DIM) - mu * mu;
    float rstd = rsqrtf(var + 1e-5f);
    u16* yr = Y + (long)row * DIM;
    yr[t]       = f2bs((v0 - mu) * rstd * w[t]       + b[t]);
    yr[t + 256] = f2bs((v1 - mu) * rstd * w[t + 256] + b[t + 256]);
    yr[t + 512] = f2bs((v2 - mu) * rstd * w[t + 512] + b[t + 512]);
}

// ---------------- bf16 MFMA GEMM, C = A[M,K] @ Bt[N,K]^T, BMxBNx64 tiles ----------------
// Staging via global_load_lds width=16 into unpadded stride-64 LDS with XOR swizzle:
// LDS[row][c] holds global chunk (c ^ (row&7)); fragment reads re-apply the XOR.
// EPI: 0 = bf16 out; 1 = f32 out + resid; 2 = bf16 out + bias + exact GELU; 3 = f32 out + resid + bias
template <int BM, int BN, int EPI>
__global__ __launch_bounds__(256) void gemm_bt(const u16* __restrict__ A,
                                               const u16* __restrict__ Bt,
                                               int M, int N, int K,
                                               u16* __restrict__ Cb,
                                               float* __restrict__ Cf,
                                               const float* __restrict__ resid,
                                               const float* __restrict__ bias) {
    constexpr int MB = BM / 32, NB = BN / 32;
    __shared__ u16 As[BM * 64];
    __shared__ u16 Bs[BN * 64];
    int m0 = blockIdx.y * BM;
    int n0 = blockIdx.x * BN;
    int t = threadIdx.x;
    int lane = t & 63, w = t >> 6;
    int quad = lane >> 4, l16 = lane & 15;
    int wr = w >> 1, wc = w & 1;
    int lr = lane >> 3, lc = lane & 7;
    int sc = (lc ^ lr) * 8;      // swizzled source chunk offset (u16 units)
    int x7 = l16 & 7;            // row&7 for fragment reads

    f32x4 acc[MB][NB];
#pragma unroll
    for (int mb = 0; mb < MB; mb++)
#pragma unroll
        for (int nb = 0; nb < NB; nb++) acc[mb][nb] = (f32x4){0.f, 0.f, 0.f, 0.f};

    for (int kt = 0; kt < K; kt += 64) {
        __syncthreads();
#pragma unroll
        for (int i = 0; i < BM / 32; i++) {
            int rb = i * 32 + w * 8;
            gld16(&A[(long)(m0 + rb + lr) * K + kt + sc], &As[rb * 64]);
        }
#pragma unroll
        for (int i = 0; i < BN / 32; i++) {
            int rb = i * 32 + w * 8;
            gld16(&Bt[(long)(n0 + rb + lr) * K + kt + sc], &Bs[rb * 64]);
        }
        __syncthreads();
#pragma unroll
        for (int kh = 0; kh < 2; kh++) {
            bf16x8 af[MB], bfr[NB];
#pragma unroll
            for (int mb = 0; mb < MB; mb++)
                af[mb] = *(const bf16x8*)&As[(wr * (BM / 2) + mb * 16 + l16) * 64 +
                                             (((kh * 4 + quad) ^ x7) * 8)];
#pragma unroll
            for (int nb = 0; nb < NB; nb++)
                bfr[nb] = *(const bf16x8*)&Bs[(wc * (BN / 2) + nb * 16 + l16) * 64 +
                                              (((kh * 4 + quad) ^ x7) * 8)];
#pragma unroll
            for (int mb = 0; mb < MB; mb++)
#pragma unroll
                for (int nb = 0; nb < NB; nb++)
                    acc[mb][nb] = __builtin_amdgcn_mfma_f32_16x16x32_bf16(af[mb], bfr[nb], acc[mb][nb], 0, 0, 0);
        }
    }

    int mbase = m0 + wr * (BM / 2), nbase = n0 + wc * (BN / 2);
#pragma unroll
    for (int mb = 0; mb < MB; mb++)
#pragma unroll
        for (int nb = 0; nb < NB; nb++) {
            int r0 = mbase + mb * 16 + quad * 4;
            int c = nbase + nb * 16 + l16;
#pragma unroll
            for (int r = 0; r < 4; r++) {
                float v = acc[mb][nb][r];
                long idx = (long)(r0 + r) * N + c;
                if (EPI == 0) {
                    Cb[idx] = f2bs(v);
                } else if (EPI == 1) {
                    Cf[idx] = resid[idx] + v;
                } else if (EPI == 2) {
                    float xg = v + bias[c];
                    Cb[idx] = f2bs(xg * 0.5f * (1.0f + erff(xg * 0.70710678118f)));
                } else {
                    Cf[idx] = resid[idx] + v + bias[c];
                }
            }
        }
}

// ---------------- flash attention: QT=128 q-rows/block, KT=128 keys/iter ----------------
// S^T formulation: QK^T MFMA computes S^T = mfma(kf, qf) so each lane's 32 scores all
// belong to q-row l16 -> softmax reductions are in-lane + 2 shuffles. PV path unchanged.
__global__ __launch_bounds__(256, 3) void attn(const u16* __restrict__ QKV, u16* __restrict__ O) {
    __shared__ u16 Ks[128 * 72];      // K rows [kv][d], stride 72
    __shared__ u16 Vs[64 * 136];      // transposed: Vs[d][kv], stride 136
    __shared__ u16 Ps[4][16 * 136];   // per-wave P tile [q][kv] (wave-private), stride 136
    int q0 = blockIdx.x * 128;
    int h = blockIdx.y;
    int b = blockIdx.z;
    int t = threadIdx.x;
    int lane = t & 63, w = t >> 6;
    int quad = lane >> 4, l16 = lane & 15;

    const long rs = 3 * DIM;  // 2304
    const u16* base = QKV + (long)b * SEQ * rs;

    bf16x8 qf[2][2];
#pragma unroll
    for (int rg = 0; rg < 2; rg++) {
        int qrow = q0 + w * 32 + rg * 16 + l16;
        qf[rg][0] = *(const bf16x8*)&base[(long)qrow * rs + h * 64 + quad * 8];
        qf[rg][1] = *(const bf16x8*)&base[(long)qrow * rs + h * 64 + 32 + quad * 8];
    }

    f32x4 o[2][4];
#pragma unroll
    for (int rg = 0; rg < 2; rg++)
#pragma unroll
        for (int jb = 0; jb < 4; jb++) o[rg][jb] = (f32x4){0.f, 0.f, 0.f, 0.f};
    float m_run[2] = {-1e30f, -1e30f};   // per-lane: running max for q-row l16
    float l_run[2] = {0.f, 0.f};

    const float L2E8 = 11.54156032f;  // 8 * log2(e)

    int kvr = t >> 1, khalf = (t & 1) * 32;
    int vp = t & 63, vo = t >> 6;

    const u16* kptr = &base[(long)kvr * rs + DIM + h * 64 + khalf];
    const u16* vptr = &base[(long)(2 * vp) * rs + 2 * DIM + h * 64 + vo * 16];
    const long kstep = (long)128 * rs;

    bf16x8 kpre[4], va0, va1, vb0, vb1;
    kpre[0] = *(const bf16x8*)&kptr[0];
    kpre[1] = *(const bf16x8*)&kptr[8];
    kpre[2] = *(const bf16x8*)&kptr[16];
    kpre[3] = *(const bf16x8*)&kptr[24];
    va0 = *(const bf16x8*)&vptr[0];
    va1 = *(const bf16x8*)&vptr[8];
    vb0 = *(const bf16x8*)&vptr[rs];
    vb1 = *(const bf16x8*)&vptr[rs + 8];

    for (int kt = 0; kt < SEQ; kt += 128) {
        __syncthreads();
        {
            *(bf16x8*)&Ks[kvr * 72 + khalf]      = kpre[0];
            *(bf16x8*)&Ks[kvr * 72 + khalf + 8]  = kpre[1];
            *(bf16x8*)&Ks[kvr * 72 + khalf + 16] = kpre[2];
            *(bf16x8*)&Ks[kvr * 72 + khalf + 24] = kpre[3];
#pragma unroll
            for (int j = 0; j < 8; j++) {
                u32 pk = (u32)(u16)va0[j] | ((u32)(u16)vb0[j] << 16);
                *(u32*)&Vs[(vo * 16 + j) * 136 + 2 * vp] = pk;
            }
#pragma unroll
            for (int j = 0; j < 8; j++) {
                u32 pk = (u32)(u16)va1[j] | ((u32)(u16)vb1[j] << 16);
                *(u32*)&Vs[(vo * 16 + 8 + j) * 136 + 2 * vp] = pk;
            }
        }
        __syncthreads();

        if (kt + 128 < SEQ) {
            kptr += kstep; vptr += kstep;
            kpre[0] = *(const bf16x8*)&kptr[0];
            kpre[1] = *(const bf16x8*)&kptr[8];
            kpre[2] = *(const bf16x8*)&kptr[16];
            kpre[3] = *(const bf16x8*)&kptr[24];
            va0 = *(const bf16x8*)&vptr[0];
            va1 = *(const bf16x8*)&vptr[8];
            vb0 = *(const bf16x8*)&vptr[rs];
            vb1 = *(const bf16x8*)&vptr[rs + 8];
        }

#pragma unroll
        for (int rg = 0; rg < 2; rg++) {
            // S^T: lane (quad,l16) gets s[jb][r] = S[q=l16][kv = jb*16 + quad*4 + r]
            f32x4 s[8];
#pragma unroll
            for (int jb = 0; jb < 8; jb++) {
                bf16x8 kf0 = *(const bf16x8*)&Ks[(jb * 16 + l16) * 72 + quad * 8];
                bf16x8 kf1 = *(const bf16x8*)&Ks[(jb * 16 + l16) * 72 + 32 + quad * 8];
                f32x4 z = (f32x4){0.f, 0.f, 0.f, 0.f};
                z = __builtin_amdgcn_mfma_f32_16x16x32_bf16(kf0, qf[rg][0], z, 0, 0, 0);
                z = __builtin_amdgcn_mfma_f32_16x16x32_bf16(kf1, qf[rg][1], z, 0, 0, 0);
                s[jb] = z;
            }

            // per-lane softmax for q-row l16: in-lane max/sum over 32, + 2 shuffles across quads
            float m1 = s[0][0];
#pragma unroll
            for (int jb = 0; jb < 8; jb++)
#pragma unroll
                for (int r = 0; r < 4; r++) m1 = fmaxf(m1, s[jb][r]);
            m1 = fmaxf(m1, __shfl_xor(m1, 16, 64));
            m1 = fmaxf(m1, __shfl_xor(m1, 32, 64));
            float mn = fmaxf(m_run[rg], m1);
            float alpha = exp2f((m_run[rg] - mn) * L2E8);
            m_run[rg] = mn;
            float mn8 = mn * L2E8;
            float rsum = 0.f;
#pragma unroll
            for (int jb = 0; jb < 8; jb++)
#pragma unroll
                for (int r = 0; r < 4; r++) {
                    float p = exp2f(fmaf(s[jb][r], L2E8, -mn8));
                    s[jb][r] = p;
                    rsum += p;
                }
            rsum += __shfl_xor(rsum, 16, 64);
            rsum += __shfl_xor(rsum, 32, 64);
            l_run[rg] = l_run[rg] * alpha + rsum;

            // broadcast alpha (owned by lane l16==q) to o rows q = quad*4+r
            float a0 = __shfl(alpha, quad * 4 + 0, 16);
            float a1 = __shfl(alpha, quad * 4 + 1, 16);
            float a2 = __shfl(alpha, quad * 4 + 2, 16);
            float a3 = __shfl(alpha, quad * 4 + 3, 16);
#pragma unroll
            for (int jb = 0; jb < 4; jb++) {
                o[rg][jb][0] *= a0; o[rg][jb][1] *= a1;
                o[rg][jb][2] *= a2; o[rg][jb][3] *= a3;
            }

            // P store: lane owns P[q=l16][kv=jb*16+quad*4 .. +3] -> one aligned 8B write/jb
#pragma unroll
            for (int jb = 0; jb < 8; jb++) {
                u32x2 pk;
                pk.x = packbf2(s[jb][0], s[jb][1]);
                pk.y = packbf2(s[jb][2], s[jb][3]);
                *(u32x2*)&Ps[w][l16 * 136 + jb * 16 + quad * 4] = pk;
            }

#pragma unroll
            for (int c = 0; c < 4; c++) {
                bf16x8 pf = *(const bf16x8*)&Ps[w][l16 * 136 + c * 32 + quad * 8];
#pragma unroll
                for (int jb = 0; jb < 4; jb++) {
                    bf16x8 vf = *(const bf16x8*)&Vs[(jb * 16 + l16) * 136 + c * 32 + quad * 8];
                    o[rg][jb] = __builtin_amdgcn_mfma_f32_16x16x32_bf16(pf, vf, o[rg][jb], 0, 0, 0);
                }
            }
        }
    }

#pragma unroll
    for (int rg = 0; rg < 2; rg++) {
        float l0 = __shfl(l_run[rg], quad * 4 + 0, 16);
        float l1 = __shfl(l_run[rg], quad * 4 + 1, 16);
        float l2 = __shfl(l_run[rg], quad * 4 + 2, 16);
        float l3 = __shfl(l_run[rg], quad * 4 + 3, 16);
        u16* orow = O + ((long)(b * SEQ + q0 + w * 32 + rg * 16)) * DIM + h * 64;
#pragma unroll
        for (int jb = 0; jb < 4; jb++) {
            u32 p01 = packbf2(o[rg][jb][0] / l0, o[rg][jb][1] / l1);
            u32 p23 = packbf2(o[rg][jb][2] / l2, o[rg][jb][3] / l3);
            int cidx = jb * 16 + l16;
            orow[(long)(quad * 4 + 0) * DIM + cidx] = (u16)p01;
            orow[(long)(quad * 4 + 1) * DIM + cidx] = (u16)(p01 >> 16);
            orow[(long)(quad * 4 + 2) * DIM + cidx] = (u16)p23;
            orow[(long)(quad * 4 + 3) * DIM + cidx] = (u16)(p23 >> 16);
        }
    }
}

extern "C" void kernel_launch(void* const* d_in, const int* in_sizes, int n_in,
                              void* d_out, int out_size, void* d_ws, size_t ws_size,
                              hipStream_t stream) {
    const float* x     = (const float*)d_in[0];
    const float* ln1w  = (const float*)d_in[1];
    const float* ln1b  = (const float*)d_in[2];
    const float* ln2w  = (const float*)d_in[3];
    const float* ln2b  = (const float*)d_in[4];
    const float* wqkv  = (const float*)d_in[5];
    const float* wproj = (const float*)d_in[6];
    const float* wfc1  = (const float*)d_in[7];
    const float* bfc1  = (const float*)d_in[8];
    const float* wfc2  = (const float*)d_in[9];
    const float* bfc2  = (const float*)d_in[10];
    float* out = (float*)d_out;

    char* ws = (char*)d_ws;
    size_t off = 0;
    auto alloc = [&](size_t bytes) {
        void* p = ws + off;
        off = (off + bytes + 255) & ~(size_t)255;
        return p;
    };
    u16* wt_qkv  = (u16*)alloc((size_t)3 * DIM * DIM * 2);
    u16* wt_proj = (u16*)alloc((size_t)DIM * DIM * 2);
    u16* wt_fc1  = (u16*)alloc((size_t)HIDDEN * DIM * 2);
    u16* wt_fc2  = (u16*)alloc((size_t)DIM * HIDDEN * 2);
    u16* hbuf    = (u16*)alloc((size_t)ROWS * DIM * 2);      // ln1 out -> attn out -> ln2 out
    u16* gbuf    = (u16*)alloc((size_t)ROWS * HIDDEN * 2);   // gelu out
    size_t qkv_bytes = (size_t)ROWS * 3 * DIM * 2;           // 37.75 MB
    u16* qkvfull = (off + qkv_bytes + 1024 <= ws_size) ? (u16*)alloc(qkv_bytes) : nullptr;

    // 1. weights -> bf16 transposed
    wtrans<<<dim3(3 * DIM / 32, DIM / 32), 256, 0, stream>>>(wqkv, wt_qkv, DIM, 3 * DIM);
    wtrans<<<dim3(DIM / 32, DIM / 32), 256, 0, stream>>>(wproj, wt_proj, DIM, DIM);
    wtrans<<<dim3(HIDDEN / 32, DIM / 32), 256, 0, stream>>>(wfc1, wt_fc1, DIM, HIDDEN);
    wtrans<<<dim3(DIM / 32, HIDDEN / 32), 256, 0, stream>>>(wfc2, wt_fc2, HIDDEN, DIM);

    // 2. ln1
    lnorm<<<ROWS, 256, 0, stream>>>(x, ln1w, ln1b, hbuf);

    // 3. qkv + attention
    if (qkvfull) {
        gemm_bt<128, 128, 0><<<dim3(3 * DIM / 128, ROWS / 128), 256, 0, stream>>>(
            hbuf, wt_qkv, ROWS, 3 * DIM, DIM, qkvfull, nullptr, nullptr, nullptr);
        attn<<<dim3(SEQ / 128, NHEAD, BATCH), 256, 0, stream>>>(qkvfull, hbuf);
    } else {
        u16* qd = (u16*)d_out;
        for (int c = 0; c < ROWS / CHUNKR; c++) {
            const u16* hA = hbuf + (size_t)c * CHUNKR * DIM;
            gemm_bt<128, 128, 0><<<dim3(3 * DIM / 128, CHUNKR / 128), 256, 0, stream>>>(
                hA, wt_qkv, CHUNKR, 3 * DIM, DIM, qd, nullptr, nullptr, nullptr);
            attn<<<dim3(SEQ / 128, NHEAD, CHUNKB), 256, 0, stream>>>(
                qd, hbuf + (size_t)c * CHUNKR * DIM);
        }
    }

    // 4. x1 = x + attn_out @ w_proj  (fp32 into d_out)
    gemm_bt<128, 64, 1><<<dim3(DIM / 64, ROWS / 128), 256, 0, stream>>>(
        hbuf, wt_proj, ROWS, DIM, DIM, nullptr, out, x, nullptr);

    // 5. ln2
    lnorm<<<ROWS, 256, 0, stream>>>(out, ln2w, ln2b, hbuf);

    // 6. g = gelu(hbuf @ w_fc1 + b_fc1)
    gemm_bt<64, 64, 2><<<dim3(HIDDEN / 64, ROWS / 64), 256, 0, stream>>>(
        hbuf, wt_fc1, ROWS, HIDDEN, DIM, gbuf, nullptr, nullptr, bfc1);

    // 7. out = x1 + g @ w_fc2 + b_fc2  (fp32, in-place over x1)
    gemm_bt<128, 64, 3><<<dim3(DIM / 64, ROWS / 128), 256, 0, stream>>>(
        gbuf, wt_fc2, ROWS, DIM, HIDDEN, nullptr, out, out, bfc2);
}